// Round 8
// baseline (451.666 us; speedup 1.0000x reference)
//
#include <hip/hip_runtime.h>

#define N_NODES 100000
#define N_EDGES 1600000
#define DIM 128

#define BK_BITS 7
#define BK_NODES 128
#define NBK ((N_NODES + BK_NODES - 1) / BK_NODES)   // 782
#define BCAP 2688                 // mean 2046/bucket, sd ~45 -> 14 sigma
#define MT_TILES ((N_NODES + 127) / 128)            // 782

typedef __attribute__((ext_vector_type(8))) short bf16x8;
typedef __attribute__((ext_vector_type(4))) float f32x4;

__device__ inline unsigned short f2bf(float f) {
    unsigned u = __builtin_bit_cast(unsigned, f);
    return (unsigned short)((u + 0x7FFFu + ((u >> 16) & 1u)) >> 16);   // RNE
}
__device__ inline float bf2f(unsigned short u) {
    unsigned v = ((unsigned)u) << 16;
    return __builtin_bit_cast(float, v);
}

// Direct global->LDS 16B DMA. LDS dest = wave-uniform base + lane*16.
__device__ __forceinline__ void gl16(const void* g, void* l) {
    __builtin_amdgcn_global_load_lds(
        (const __attribute__((address_space(1))) void*)g,
        (__attribute__((address_space(3))) void*)l, 16, 0, 0);
}

// 512-thread stage of a 128-row x 256B tile. WAVE-LOCAL: wave w stages
// exactly rows [w*16, w*16+16) -- matches the wave's fragment-read strip.
// Swizzle: byte-in-row ^= (row&7)<<4 (conflict-free ds_read_b128).
__device__ __forceinline__ void stage512(const void* gbase, void* lds, int t) {
    const int wvS = t >> 6, lnS = t & 63;        // 8 waves
    #pragma unroll
    for (int k = 0; k < 4; ++k) {
        int chunk = wvS * 4 + k;                 // 0..31 (1KB each)
        int r = chunk * 4 + (lnS >> 4);          // row 0..127, in [wvS*16, wvS*16+16)
        int gb = ((lnS & 15) * 16) ^ ((r & 7) << 4);
        gl16((const char*)gbase + (size_t)r * 256 + gb,
             (char*)lds + chunk * 1024);
    }
}

// Swizzled bf16x8 fragment read (matching the staging swizzle).
__device__ __forceinline__ bf16x8 frag8(const unsigned short* lds, int row, int bo) {
    return *(const bf16x8*)((const char*)lds + row * 256 + (bo ^ ((row & 7) << 4)));
}

// ===========================================================================
// Combined one-time converts: x -> bf16 AND all 4 weight transposes.
// blocks [0, 12500): x ; blocks [12500, 12756): weights
// ===========================================================================
__global__ __launch_bounds__(256) void cvt_k(const float* __restrict__ x,
                                             unsigned short* __restrict__ xb,
                                             const float* __restrict__ Wa,
                                             const float* __restrict__ Wb,
                                             const float* __restrict__ Wc,
                                             const float* __restrict__ Wd,
                                             unsigned short* __restrict__ wt)
{
    int b = blockIdx.x;
    if (b < 12500) {
        int i = (b * 256 + threadIdx.x) * 4;
        float4 v = *(const float4*)(x + i);
        unsigned short o[4] = {f2bf(v.x), f2bf(v.y), f2bf(v.z), f2bf(v.w)};
        xb[i] = o[0]; xb[i+1] = o[1]; xb[i+2] = o[2]; xb[i+3] = o[3];
    } else {
        int id = (b - 12500) * 256 + threadIdx.x;      // 0..65535
        int which = id >> 14, rem = id & 16383;
        const float* W = (which == 0) ? Wa : (which == 1) ? Wb : (which == 2) ? Wc : Wd;
        int n = rem >> 7, k = rem & 127;
        wt[which * 16384 + n * DIM + k] = f2bf(W[k * DIM + n]);
    }
}

// ===========================================================================
// Block-aggregated bucket fill: 8192 edges/block. dst cached in registers
// between the histogram pass and the scatter pass (-6.4MB global re-read).
// ===========================================================================
__global__ __launch_bounds__(512) void bfill2_k(const int* __restrict__ ei,
                                                int* __restrict__ bcursor,
                                                int* __restrict__ bbuf)
{
    __shared__ int hist[NBK];
    __shared__ int cur[NBK];
    const int t = threadIdx.x;
    const int e0 = blockIdx.x * 8192;

    for (int b = t; b < NBK; b += 512) hist[b] = 0;
    __syncthreads();
    int dreg[16];
    #pragma unroll
    for (int i = 0; i < 16; ++i) {
        int e = e0 + i * 512 + t;
        dreg[i] = (e < N_EDGES) ? ei[N_EDGES + e] : -1;
        if (dreg[i] >= 0) atomicAdd(&hist[dreg[i] >> BK_BITS], 1);
    }
    __syncthreads();
    for (int b = t; b < NBK; b += 512) {
        int h = hist[b];
        cur[b] = h ? atomicAdd(bcursor + b, h) : 0;
    }
    __syncthreads();
    #pragma unroll
    for (int i = 0; i < 16; ++i) {
        int e = e0 + i * 512 + t;
        int dst = dreg[i];
        if (dst >= 0) {
            int src = ei[e];
            int b = dst >> BK_BITS;
            int pos = atomicAdd(&cur[b], 1);
            if (pos < BCAP) bbuf[b * BCAP + pos] = ((dst & (BK_NODES - 1)) << 17) | src;
        }
    }
}

// ===========================================================================
// ONE-TIME counting sort per bucket -> CSR (nstart/ndeg), bbuf in place.
// ===========================================================================
__global__ __launch_bounds__(256) void bsort_k(const int* __restrict__ bcursor,
                                               int* __restrict__ bbuf,
                                               int* __restrict__ nstart,
                                               int* __restrict__ ndeg)
{
    __shared__ int elist[BCAP];
    __shared__ int bins[BK_NODES];
    __shared__ int cur[BK_NODES];
    __shared__ int scanb[BK_NODES];

    const int t = threadIdx.x;
    const int b = blockIdx.x;

    if (t < BK_NODES) bins[t] = 0;
    __syncthreads();

    int n = bcursor[b];
    if (n > BCAP) n = BCAP;
    int* bp = bbuf + b * BCAP;

    int wreg[(BCAP + 255) / 256];                 // 11
    const int nIter = (n + 255) >> 8;
    #pragma unroll
    for (int i = 0; i < (BCAP + 255) / 256; ++i) wreg[i] = -1;
    for (int i = 0; i < nIter; ++i) {
        int idx = t + (i << 8);
        if (idx < n) {
            int word = bp[idx];
            wreg[i] = word;
            atomicAdd(&bins[word >> 17], 1);
        }
    }
    __syncthreads();

    if (t < BK_NODES) scanb[t] = bins[t];
    __syncthreads();
    #pragma unroll
    for (int off = 1; off < BK_NODES; off <<= 1) {
        int add = (t >= off && t < BK_NODES) ? scanb[t - off] : 0;
        __syncthreads();
        if (t < BK_NODES) scanb[t] += add;
        __syncthreads();
    }
    if (t < BK_NODES) {
        cur[t] = scanb[t] - bins[t];
        int node = b * BK_NODES + t;
        if (node < N_NODES) {
            nstart[node] = b * BCAP + (scanb[t] - bins[t]);
            ndeg[node] = bins[t];
        }
    }
    __syncthreads();

    for (int i = 0; i < nIter; ++i) {
        int word = wreg[i];
        if (word >= 0) {
            int dl = word >> 17;
            int pos = atomicAdd(&cur[dl], 1);
            elist[pos] = word & 0x1FFFF;
        }
    }
    __syncthreads();

    for (int i = t; i < n; i += 256) bp[i] = elist[i];      // coalesced writeback
}

// ===========================================================================
// CSR mean-aggregation gather (bf16): unroll-4 (proven round-4/6 version).
// ===========================================================================
__global__ __launch_bounds__(512) void agg_csr_k(const unsigned short* __restrict__ xb,
                                                 const int* __restrict__ elist,
                                                 const int* __restrict__ nstart,
                                                 const int* __restrict__ ndeg,
                                                 unsigned short* __restrict__ ab)
{
    const int t = threadIdx.x;
    const int wv = t >> 6;              // wave in block: 0..7
    const int lane = t & 63;
    const int qw = lane >> 4;           // 0..3
    const int c  = lane & 15;           // col chunk: cols c*8 .. c*8+7
    const int sub = qw & 1;             // which half of the edge list
    const int nn  = qw >> 1;            // node within the pair

    const int g  = blockIdx.x * 8 + wv; // global wave id
    const int NW = gridDim.x * 8;       // total waves

    for (int n0 = g * 2; n0 < N_NODES; n0 += NW * 2) {
        int node = n0 + nn;
        bool valid = node < N_NODES;
        int beg = 0, deg = 0;
        if (valid) { beg = nstart[node]; deg = ndeg[node]; }
        int mid = beg + ((deg + 1) >> 1);
        int end = beg + deg;
        int lo = sub ? mid : beg;
        int hi = sub ? end : mid;

        float a[8];
        #pragma unroll
        for (int u = 0; u < 8; ++u) a[u] = 0.f;

        int e = lo;
        for (; e + 4 <= hi; e += 4) {
            int s0 = elist[e], s1 = elist[e + 1], s2 = elist[e + 2], s3 = elist[e + 3];
            bf16x8 v0 = *(const bf16x8*)(xb + s0 * DIM + c * 8);
            bf16x8 v1 = *(const bf16x8*)(xb + s1 * DIM + c * 8);
            bf16x8 v2 = *(const bf16x8*)(xb + s2 * DIM + c * 8);
            bf16x8 v3 = *(const bf16x8*)(xb + s3 * DIM + c * 8);
            #pragma unroll
            for (int u = 0; u < 8; ++u)
                a[u] += (bf2f((unsigned short)v0[u]) + bf2f((unsigned short)v1[u]))
                      + (bf2f((unsigned short)v2[u]) + bf2f((unsigned short)v3[u]));
        }
        for (; e < hi; ++e) {
            int s0 = elist[e];
            bf16x8 v0 = *(const bf16x8*)(xb + s0 * DIM + c * 8);
            #pragma unroll
            for (int u = 0; u < 8; ++u) a[u] += bf2f((unsigned short)v0[u]);
        }

        // combine the two half-sums for this node (lanes qw0<->qw1, qw2<->qw3)
        #pragma unroll
        for (int u = 0; u < 8; ++u) a[u] += __shfl_xor(a[u], 16, 64);

        if (valid && sub == 0) {
            float inv = 1.0f / fmaxf((float)deg, 1.0f);
            bf16x8 xv = *(const bf16x8*)(xb + node * DIM + c * 8);
            bf16x8 o;
            #pragma unroll
            for (int u = 0; u < 8; ++u)
                o[u] = (short)f2bf(bf2f((unsigned short)xv[u]) + a[u] * inv);
            *(bf16x8*)(ab + node * DIM + c * 8) = o;
        }
    }
}

// ===========================================================================
// Stats-only GEMM1 (one 128-row tile per block, 512 threads, wave-local
// 16-row strips): LDS 65KB -> 2 blocks/CU -> 16 waves/CU (2x round-6).
// ===========================================================================
__global__ __launch_bounds__(512) void gemm1_stats_k(
    const unsigned short* __restrict__ ab,
    const unsigned short* __restrict__ Wt, const float* __restrict__ bias,
    float* __restrict__ colsum, float* __restrict__ colsq)
{
    __shared__ unsigned short Alds[128 * 128];        // 32KB
    __shared__ unsigned short Wlds[128 * 128];        // 32KB
    __shared__ float cstat[256];

    const int t = threadIdx.x;
    const int row0 = blockIdx.x * 128;
    if (t < 256) cstat[t] = 0.f;

    stage512((const char*)ab + (size_t)row0 * 256, Alds, t);
    stage512(Wt, Wlds, t);
    __syncthreads();                 // drains vmcnt; Wlds visible to all waves

    const int w = t >> 6, lane = t & 63;
    const int m = lane & 15, q = lane >> 4;

    f32x4 acc[8];
    #pragma unroll
    for (int ct = 0; ct < 8; ++ct) acc[ct] = (f32x4)0.f;
    #pragma unroll
    for (int kb = 0; kb < 4; ++kb) {
        int bo = kb * 64 + q * 16;
        bf16x8 af = frag8(Alds, w * 16 + m, bo);
        #pragma unroll
        for (int ct = 0; ct < 8; ++ct)
            acc[ct] = __builtin_amdgcn_mfma_f32_16x16x32_bf16(
                af, frag8(Wlds, ct * 16 + m, bo), acc[ct], 0, 0, 0);
    }

    int rbase = row0 + w * 16 + q * 4;
    #pragma unroll
    for (int ct = 0; ct < 8; ++ct) {
        int col = ct * 16 + m;
        float bb = bias[col];
        float ps = 0.f, pq = 0.f;
        #pragma unroll
        for (int r = 0; r < 4; ++r) {
            if (rbase + r < N_NODES) {
                float v = acc[ct][r] + bb;
                ps += v; pq += v * v;
            }
        }
        atomicAdd(&cstat[col], ps);
        atomicAdd(&cstat[128 + col], pq);
    }
    __syncthreads();
    if (t < 128) {
        atomicAdd(colsum + t, cstat[t]);
        atomicAdd(colsq + t, cstat[128 + t]);
    }
}

// ===========================================================================
// Fused MLP (one tile per block, 512 threads, wave-local strips):
// bnstats folded -> GEMM1 -> BN+ReLU t into own A strip -> W2 restage ->
// GEMM2 -> out. LDS 65.5KB -> 2 blocks/CU -> 16 waves/CU.
// mode 1: bf16 relu -> xbout ; mode 0: fp32 -> outf
// ===========================================================================
__global__ __launch_bounds__(512) void fused_mlp_k(
    const unsigned short* __restrict__ ab,
    const float* __restrict__ colsum, const float* __restrict__ colsq,
    const float* __restrict__ gamma, const float* __restrict__ beta,
    const unsigned short* __restrict__ Wt1, const float* __restrict__ b1,
    const unsigned short* __restrict__ Wt2, const float* __restrict__ b2,
    float* __restrict__ outf, unsigned short* __restrict__ xbout, int mode)
{
    __shared__ unsigned short Alds[128 * 128];        // 32KB
    __shared__ unsigned short Wlds[128 * 128];        // 32KB
    __shared__ float ssc[384];                        // scale | shift | b1

    const int t = threadIdx.x;
    const int row0 = blockIdx.x * 128;

    if (t < 128) {
        const float inv_n = 1.0f / (float)N_NODES;
        float mu = colsum[t] * inv_n;
        float var = colsq[t] * inv_n - mu * mu;       // biased variance (torch BN)
        float sc = gamma[t] * rsqrtf(var + 1e-5f);
        ssc[t] = sc;
        ssc[128 + t] = beta[t] - mu * sc;
        ssc[256 + t] = b1[t];
    }

    stage512((const char*)ab + (size_t)row0 * 256, Alds, t);
    stage512(Wt1, Wlds, t);
    __syncthreads();

    const int w = t >> 6, lane = t & 63;
    const int m = lane & 15, q = lane >> 4;

    // ---- GEMM1 (wave-own 16-row strip) ----
    f32x4 acc[8];
    #pragma unroll
    for (int ct = 0; ct < 8; ++ct) acc[ct] = (f32x4)0.f;
    #pragma unroll
    for (int kb = 0; kb < 4; ++kb) {
        int bo = kb * 64 + q * 16;
        bf16x8 af = frag8(Alds, w * 16 + m, bo);
        #pragma unroll
        for (int ct = 0; ct < 8; ++ct)
            acc[ct] = __builtin_amdgcn_mfma_f32_16x16x32_bf16(
                af, frag8(Wlds, ct * 16 + m, bo), acc[ct], 0, 0, 0);
    }
    __syncthreads();                 // all waves done reading W1 (and A)

    // ---- t = relu(BN(acc+b1)) -> own A strip; restage W2 over W1 ----
    #pragma unroll
    for (int ct = 0; ct < 8; ++ct) {
        int col = ct * 16 + m;
        float sc = ssc[col], sh = ssc[128 + col], bb = ssc[256 + col];
        #pragma unroll
        for (int r = 0; r < 4; ++r) {
            int row = w * 16 + q * 4 + r;
            float v = acc[ct][r] + bb;
            *(unsigned short*)((char*)Alds + row * 256 +
                               ((col * 2) ^ ((row & 7) << 4)))
                = f2bf(fmaxf(v * sc + sh, 0.f));
        }
    }
    stage512(Wt2, Wlds, t);
    __syncthreads();                 // drains t-writes + W2 DMA

    // ---- GEMM2 ----
    #pragma unroll
    for (int ct = 0; ct < 8; ++ct) acc[ct] = (f32x4)0.f;
    #pragma unroll
    for (int kb = 0; kb < 4; ++kb) {
        int bo = kb * 64 + q * 16;
        bf16x8 af = frag8(Alds, w * 16 + m, bo);
        #pragma unroll
        for (int ct = 0; ct < 8; ++ct)
            acc[ct] = __builtin_amdgcn_mfma_f32_16x16x32_bf16(
                af, frag8(Wlds, ct * 16 + m, bo), acc[ct], 0, 0, 0);
    }

    // ---- epilogue ----
    int rbase = row0 + w * 16 + q * 4;
    #pragma unroll
    for (int ct = 0; ct < 8; ++ct) {
        int col = ct * 16 + m;
        float bb = b2[col];
        #pragma unroll
        for (int r = 0; r < 4; ++r) {
            int gr = rbase + r;
            if (gr < N_NODES) {
                float v = acc[ct][r] + bb;
                if (mode) xbout[gr * DIM + col] = f2bf(fmaxf(v, 0.f));
                else      outf[gr * DIM + col] = v;
            }
        }
    }
}

// ---------------------------------------------------------------------------
// Workspace (float units):
//   xb     @ 12,800,512 : 12.8M ushort (6.4M floats)  [x_bf16 / interlayer]
//   ab     @ 19,200,512 : 12.8M ushort (6.4M floats)  [agg output]
//   ints   @ 25,600,512 : bbuf[NBK*BCAP=2,102,016] | bcursor[782] | pad[2] |
//                         stats[512 floats: cs0 cq0 cs1 cq1] |
//                         nstart[100,000] | ndeg[100,000] | Wt x4 (bf16)
// One memset covers bcursor..stats (1296 ints).
// ---------------------------------------------------------------------------
extern "C" void kernel_launch(void* const* d_in, const int* in_sizes, int n_in,
                              void* d_out, int out_size, void* d_ws, size_t ws_size,
                              hipStream_t stream)
{
    const float* x    = (const float*)d_in[0];
    const int*   ei   = (const int*)d_in[1];
    const float* W1_0 = (const float*)d_in[2];
    const float* b1_0 = (const float*)d_in[3];
    const float* g_0  = (const float*)d_in[4];
    const float* be_0 = (const float*)d_in[5];
    const float* W2_0 = (const float*)d_in[6];
    const float* b2_0 = (const float*)d_in[7];
    const float* W1_1 = (const float*)d_in[8];
    const float* b1_1 = (const float*)d_in[9];
    const float* g_1  = (const float*)d_in[10];
    const float* be_1 = (const float*)d_in[11];
    const float* W2_1 = (const float*)d_in[12];
    const float* b2_1 = (const float*)d_in[13];
    float* out = (float*)d_out;
    float* ws  = (float*)d_ws;

    unsigned short* xb = (unsigned short*)(ws + 12800512);
    unsigned short* ab = (unsigned short*)(ws + 19200512);
    int* ibase    = (int*)(ws + 25600512);
    int* bbuf     = ibase;
    int* bcursor  = ibase + NBK * BCAP;
    float* stats  = (float*)(bcursor + NBK + 2);       // 512 floats
    float* cs0 = stats, *cq0 = stats + 128, *cs1 = stats + 256, *cq1 = stats + 384;
    int* nstart   = (int*)(stats + 512);
    int* ndeg     = nstart + N_NODES;
    unsigned short* wt10 = (unsigned short*)(ndeg + N_NODES);
    unsigned short* wt20 = wt10 + 16384;
    unsigned short* wt11 = wt10 + 32768;
    unsigned short* wt21 = wt10 + 49152;

    dim3 blk(256);
    int fill_blocks = (N_EDGES + 8191) / 8192;         // 196

    // ---- one-time converts + bucket build + one-time counting sort ----
    cvt_k<<<12756, blk, 0, stream>>>(x, xb, W1_0, W2_0, W1_1, W2_1, wt10);
    hipMemsetAsync(bcursor, 0, (NBK + 2 + 512) * sizeof(int), stream);
    bfill2_k<<<fill_blocks, 512, 0, stream>>>(ei, bcursor, bbuf);
    bsort_k<<<NBK, blk, 0, stream>>>(bcursor, bbuf, nstart, ndeg);

    // ---- layer 0 ----
    agg_csr_k<<<1024, 512, 0, stream>>>(xb, bbuf, nstart, ndeg, ab);
    gemm1_stats_k<<<MT_TILES, 512, 0, stream>>>(ab, wt10, b1_0, cs0, cq0);
    fused_mlp_k<<<MT_TILES, 512, 0, stream>>>(ab, cs0, cq0, g_0, be_0,
                                              wt10, b1_0, wt20, b2_0,
                                              nullptr, xb, 1);

    // ---- layer 1 ----
    agg_csr_k<<<1024, 512, 0, stream>>>(xb, bbuf, nstart, ndeg, ab);
    gemm1_stats_k<<<MT_TILES, 512, 0, stream>>>(ab, wt11, b1_1, cs1, cq1);
    fused_mlp_k<<<MT_TILES, 512, 0, stream>>>(ab, cs1, cq1, g_1, be_1,
                                              wt11, b1_1, wt21, b2_1,
                                              out, nullptr, 0);
}

// Round 9
// 450.000 us; speedup vs baseline: 1.0037x; 1.0037x over previous
//
#include <hip/hip_runtime.h>

#define N_NODES 100000
#define N_EDGES 1600000
#define DIM 128

#define BK_BITS 7
#define BK_NODES 128
#define NBK ((N_NODES + BK_NODES - 1) / BK_NODES)   // 782
#define BCAP 2688                 // mean 2046/bucket, sd ~45 -> 14 sigma
#define MT_TILES ((N_NODES + 127) / 128)            // 782

typedef __attribute__((ext_vector_type(8))) short bf16x8;
typedef __attribute__((ext_vector_type(4))) float f32x4;

__device__ inline unsigned short f2bf(float f) {
    unsigned u = __builtin_bit_cast(unsigned, f);
    return (unsigned short)((u + 0x7FFFu + ((u >> 16) & 1u)) >> 16);   // RNE
}
__device__ inline float bf2f(unsigned short u) {
    unsigned v = ((unsigned)u) << 16;
    return __builtin_bit_cast(float, v);
}

// Direct global->LDS 16B DMA. LDS dest = wave-uniform base + lane*16.
__device__ __forceinline__ void gl16(const void* g, void* l) {
    __builtin_amdgcn_global_load_lds(
        (const __attribute__((address_space(1))) void*)g,
        (__attribute__((address_space(3))) void*)l, 16, 0, 0);
}

// 256-thread stage of a 128-row x 256B tile: linear LDS dest, inverse-
// swizzled global src. Swizzle: byte-in-row ^= (row&7)<<4.
__device__ __forceinline__ void stage_tile(const void* gbase, void* lds, int t) {
    const int wvS = t >> 6, lnS = t & 63;
    #pragma unroll
    for (int k = 0; k < 8; ++k) {
        int chunk = wvS * 8 + k;                 // 0..31 (1KB each)
        int r = chunk * 4 + (lnS >> 4);          // row 0..127
        int gb = ((lnS & 15) * 16) ^ ((r & 7) << 4);
        gl16((const char*)gbase + (size_t)r * 256 + gb,
             (char*)lds + chunk * 1024);
    }
}

// Swizzled bf16x8 fragment read (matching the staging swizzle).
__device__ __forceinline__ bf16x8 frag8(const unsigned short* lds, int row, int bo) {
    return *(const bf16x8*)((const char*)lds + row * 256 + (bo ^ ((row & 7) << 4)));
}

// ===========================================================================
// Combined one-time converts: x -> bf16 AND all 4 weight transposes.
// ===========================================================================
__global__ __launch_bounds__(256) void cvt_k(const float* __restrict__ x,
                                             unsigned short* __restrict__ xb,
                                             const float* __restrict__ Wa,
                                             const float* __restrict__ Wb,
                                             const float* __restrict__ Wc,
                                             const float* __restrict__ Wd,
                                             unsigned short* __restrict__ wt)
{
    int b = blockIdx.x;
    if (b < 12500) {
        int i = (b * 256 + threadIdx.x) * 4;
        float4 v = *(const float4*)(x + i);
        unsigned short o[4] = {f2bf(v.x), f2bf(v.y), f2bf(v.z), f2bf(v.w)};
        xb[i] = o[0]; xb[i+1] = o[1]; xb[i+2] = o[2]; xb[i+3] = o[3];
    } else {
        int id = (b - 12500) * 256 + threadIdx.x;      // 0..65535
        int which = id >> 14, rem = id & 16383;
        const float* W = (which == 0) ? Wa : (which == 1) ? Wb : (which == 2) ? Wc : Wd;
        int n = rem >> 7, k = rem & 127;
        wt[which * 16384 + n * DIM + k] = f2bf(W[k * DIM + n]);
    }
}

// ===========================================================================
// Block-aggregated bucket fill: 8192 edges/block (round-6 proven version).
// ===========================================================================
__global__ __launch_bounds__(512) void bfill2_k(const int* __restrict__ ei,
                                                int* __restrict__ bcursor,
                                                int* __restrict__ bbuf)
{
    __shared__ int hist[NBK];
    __shared__ int cur[NBK];
    const int t = threadIdx.x;
    const int e0 = blockIdx.x * 8192;

    for (int b = t; b < NBK; b += 512) hist[b] = 0;
    __syncthreads();
    #pragma unroll
    for (int i = 0; i < 16; ++i) {
        int e = e0 + i * 512 + t;
        if (e < N_EDGES) atomicAdd(&hist[ei[N_EDGES + e] >> BK_BITS], 1);
    }
    __syncthreads();
    for (int b = t; b < NBK; b += 512) {
        int h = hist[b];
        cur[b] = h ? atomicAdd(bcursor + b, h) : 0;
    }
    __syncthreads();
    #pragma unroll
    for (int i = 0; i < 16; ++i) {
        int e = e0 + i * 512 + t;
        if (e < N_EDGES) {
            int src = ei[e];
            int dst = ei[N_EDGES + e];
            int b = dst >> BK_BITS;
            int pos = atomicAdd(&cur[b], 1);
            if (pos < BCAP) bbuf[b * BCAP + pos] = ((dst & (BK_NODES - 1)) << 17) | src;
        }
    }
}

// ===========================================================================
// ONE-TIME counting sort per bucket -> CSR (nstart/ndeg), bbuf in place.
// ===========================================================================
__global__ __launch_bounds__(256) void bsort_k(const int* __restrict__ bcursor,
                                               int* __restrict__ bbuf,
                                               int* __restrict__ nstart,
                                               int* __restrict__ ndeg)
{
    __shared__ int elist[BCAP];
    __shared__ int bins[BK_NODES];
    __shared__ int cur[BK_NODES];
    __shared__ int scanb[BK_NODES];

    const int t = threadIdx.x;
    const int b = blockIdx.x;

    if (t < BK_NODES) bins[t] = 0;
    __syncthreads();

    int n = bcursor[b];
    if (n > BCAP) n = BCAP;
    int* bp = bbuf + b * BCAP;

    int wreg[(BCAP + 255) / 256];                 // 11
    const int nIter = (n + 255) >> 8;
    #pragma unroll
    for (int i = 0; i < (BCAP + 255) / 256; ++i) wreg[i] = -1;
    for (int i = 0; i < nIter; ++i) {
        int idx = t + (i << 8);
        if (idx < n) {
            int word = bp[idx];
            wreg[i] = word;
            atomicAdd(&bins[word >> 17], 1);
        }
    }
    __syncthreads();

    if (t < BK_NODES) scanb[t] = bins[t];
    __syncthreads();
    #pragma unroll
    for (int off = 1; off < BK_NODES; off <<= 1) {
        int add = (t >= off && t < BK_NODES) ? scanb[t - off] : 0;
        __syncthreads();
        if (t < BK_NODES) scanb[t] += add;
        __syncthreads();
    }
    if (t < BK_NODES) {
        cur[t] = scanb[t] - bins[t];
        int node = b * BK_NODES + t;
        if (node < N_NODES) {
            nstart[node] = b * BCAP + (scanb[t] - bins[t]);
            ndeg[node] = bins[t];
        }
    }
    __syncthreads();

    for (int i = 0; i < nIter; ++i) {
        int word = wreg[i];
        if (word >= 0) {
            int dl = word >> 17;
            int pos = atomicAdd(&cur[dl], 1);
            elist[pos] = word & 0x1FFFF;
        }
    }
    __syncthreads();

    for (int i = t; i < n; i += 256) bp[i] = elist[i];      // coalesced writeback
}

// ===========================================================================
// FUSED aggregation + BN-stats GEMM. Block = tile = bucket (128 nodes,
// 782 blocks, 512 thr). Phase 1: the PROVEN round-6 gather inner loop
// (2 nodes/wave-iter, sub-split halves, unroll-4), writing rows to global
// ab AND a 32KB swizzled LDS tile. Phase 2: register-lean MFMA
// (ct-outer; W fragments direct from L2-resident global Wt) accumulating
// colsum/colsq. Deletes the separate gemm1_stats pass (26MB read + dispatch
// per layer). LDS 33.8KB -> 4 blocks/CU.
// ===========================================================================
__global__ __launch_bounds__(512) void aggstats_k(
    const unsigned short* __restrict__ xb,
    const int* __restrict__ elist,
    const int* __restrict__ nstart,
    const int* __restrict__ ndeg,
    unsigned short* __restrict__ ab,
    const unsigned short* __restrict__ Wt,
    const float* __restrict__ bias,
    float* __restrict__ colsum, float* __restrict__ colsq)
{
    __shared__ unsigned short Alds[128 * 128];   // 32KB
    __shared__ float cstat[256];

    const int t = threadIdx.x;
    const int wv = t >> 6;              // wave 0..7 -> owns rows [wv*16, wv*16+16)
    const int lane = t & 63;
    const int qw = lane >> 4;
    const int c  = lane & 15;           // col chunk c*8..c*8+7
    const int sub = qw & 1;
    const int nn  = qw >> 1;
    const int tile = blockIdx.x;

    if (t < 256) cstat[t] = 0.f;
    if (tile == MT_TILES - 1) {         // zero tail-garbage rows (uniform branch)
        #pragma unroll
        for (int i = 0; i < 4; ++i)
            *(bf16x8*)((char*)Alds + t * 64 + i * 16) = (bf16x8)(short)0;
    }
    __syncthreads();

    // ---------------- phase 1: gather (round-6 inner loop) ----------------
    for (int p = 0; p < 8; ++p) {
        int node = tile * 128 + wv * 16 + p * 2 + nn;
        bool valid = node < N_NODES;
        int beg = 0, deg = 0;
        if (valid) { beg = nstart[node]; deg = ndeg[node]; }
        int mid = beg + ((deg + 1) >> 1);
        int end = beg + deg;
        int lo = sub ? mid : beg;
        int hi = sub ? end : mid;

        float a[8];
        #pragma unroll
        for (int u = 0; u < 8; ++u) a[u] = 0.f;

        int e = lo;
        for (; e + 4 <= hi; e += 4) {
            int s0 = elist[e], s1 = elist[e + 1], s2 = elist[e + 2], s3 = elist[e + 3];
            bf16x8 v0 = *(const bf16x8*)(xb + s0 * DIM + c * 8);
            bf16x8 v1 = *(const bf16x8*)(xb + s1 * DIM + c * 8);
            bf16x8 v2 = *(const bf16x8*)(xb + s2 * DIM + c * 8);
            bf16x8 v3 = *(const bf16x8*)(xb + s3 * DIM + c * 8);
            #pragma unroll
            for (int u = 0; u < 8; ++u)
                a[u] += (bf2f((unsigned short)v0[u]) + bf2f((unsigned short)v1[u]))
                      + (bf2f((unsigned short)v2[u]) + bf2f((unsigned short)v3[u]));
        }
        for (; e < hi; ++e) {
            int s0 = elist[e];
            bf16x8 v0 = *(const bf16x8*)(xb + s0 * DIM + c * 8);
            #pragma unroll
            for (int u = 0; u < 8; ++u) a[u] += bf2f((unsigned short)v0[u]);
        }

        #pragma unroll
        for (int u = 0; u < 8; ++u) a[u] += __shfl_xor(a[u], 16, 64);

        if (valid && sub == 0) {
            float inv = 1.0f / fmaxf((float)deg, 1.0f);
            bf16x8 xv = *(const bf16x8*)(xb + node * DIM + c * 8);
            bf16x8 o;
            #pragma unroll
            for (int u = 0; u < 8; ++u)
                o[u] = (short)f2bf(bf2f((unsigned short)xv[u]) + a[u] * inv);
            *(bf16x8*)(ab + node * DIM + c * 8) = o;           // global (for fused)
            int row = wv * 16 + p * 2 + nn;
            *(bf16x8*)((char*)Alds + row * 256 +
                       ((c * 16) ^ ((row & 7) << 4))) = o;     // LDS (for stats)
        }
    }
    __syncthreads();

    // ---------------- phase 2: stats MFMA (wave-local strip) ----------------
    const int m = lane & 15, q = lane >> 4;
    for (int ct = 0; ct < 8; ++ct) {
        f32x4 acc = (f32x4)0.f;
        #pragma unroll
        for (int kb = 0; kb < 4; ++kb) {
            int bo = kb * 64 + q * 16;
            bf16x8 af = frag8(Alds, wv * 16 + m, bo);
            bf16x8 wf = *(const bf16x8*)(Wt + (ct * 16 + m) * DIM + kb * 32 + q * 8);
            acc = __builtin_amdgcn_mfma_f32_16x16x32_bf16(af, wf, acc, 0, 0, 0);
        }
        int col = ct * 16 + m;
        float bb = bias[col];
        int rbase = tile * 128 + wv * 16 + q * 4;
        float ps = 0.f, pq = 0.f;
        #pragma unroll
        for (int r = 0; r < 4; ++r) {
            if (rbase + r < N_NODES) {
                float v = acc[r] + bb;
                ps += v; pq += v * v;
            }
        }
        atomicAdd(&cstat[col], ps);
        atomicAdd(&cstat[128 + col], pq);
    }
    __syncthreads();
    if (t < 128) {
        atomicAdd(colsum + t, cstat[t]);
        atomicAdd(colsq + t, cstat[128 + t]);
    }
}

// ===========================================================================
// Fused MLP (round-6 proven 256-thr version): bnstats folded -> GEMM1 ->
// BN+ReLU t into LDS -> W2 restage -> GEMM2 -> out.
// mode 1: bf16 relu -> xbout ; mode 0: fp32 -> outf
// ===========================================================================
__global__ __launch_bounds__(256) void fused_mlp_k(
    const unsigned short* __restrict__ ab,
    const float* __restrict__ colsum, const float* __restrict__ colsq,
    const float* __restrict__ gamma, const float* __restrict__ beta,
    const unsigned short* __restrict__ Wt1, const float* __restrict__ b1,
    const unsigned short* __restrict__ Wt2, const float* __restrict__ b2,
    float* __restrict__ outf, unsigned short* __restrict__ xbout, int mode)
{
    __shared__ unsigned short Alds[128 * 128];
    __shared__ unsigned short Wlds[128 * 128];
    __shared__ float ssc[384];    // scale | shift | b1

    const int t = threadIdx.x;
    const int row0 = blockIdx.x * 128;

    if (t < 128) {
        const float inv_n = 1.0f / (float)N_NODES;
        float mu = colsum[t] * inv_n;
        float var = colsq[t] * inv_n - mu * mu;   // biased variance (torch BN)
        float sc = gamma[t] * rsqrtf(var + 1e-5f);
        ssc[t] = sc;
        ssc[128 + t] = beta[t] - mu * sc;
        ssc[256 + t] = b1[t];
    }

    stage_tile((const char*)ab + (size_t)row0 * 256, Alds, t);
    stage_tile(Wt1, Wlds, t);
    __syncthreads();

    const int w = t >> 6, lane = t & 63;
    const int m = lane & 15, q = lane >> 4;

    f32x4 acc[2][8];
    #pragma unroll
    for (int i = 0; i < 2; ++i)
        #pragma unroll
        for (int ct = 0; ct < 8; ++ct) acc[i][ct] = (f32x4)0.f;

    #pragma unroll
    for (int kb = 0; kb < 4; ++kb) {
        int bo = kb * 64 + q * 16;
        bf16x8 af0 = frag8(Alds, (w * 2 + 0) * 16 + m, bo);
        bf16x8 af1 = frag8(Alds, (w * 2 + 1) * 16 + m, bo);
        #pragma unroll
        for (int ct = 0; ct < 8; ++ct) {
            bf16x8 bfv = frag8(Wlds, ct * 16 + m, bo);
            acc[0][ct] = __builtin_amdgcn_mfma_f32_16x16x32_bf16(af0, bfv, acc[0][ct], 0, 0, 0);
            acc[1][ct] = __builtin_amdgcn_mfma_f32_16x16x32_bf16(af1, bfv, acc[1][ct], 0, 0, 0);
        }
    }

    __syncthreads();   // all waves done reading Alds (A) and Wlds (W1)

    // BN + ReLU epilogue: scatter t into Alds (swizzled bf16), restage W2.
    #pragma unroll
    for (int ct = 0; ct < 8; ++ct) {
        int col = ct * 16 + m;
        float sc = ssc[col], sh = ssc[128 + col], bb = ssc[256 + col];
        #pragma unroll
        for (int i = 0; i < 2; ++i) {
            int rr0 = (w * 2 + i) * 16 + q * 4;
            #pragma unroll
            for (int r = 0; r < 4; ++r) {
                int row = rr0 + r;
                float v = acc[i][ct][r] + bb;
                float tt = fmaxf(v * sc + sh, 0.f);
                *(unsigned short*)((char*)Alds + row * 256 +
                                   ((col * 2) ^ ((row & 7) << 4))) = f2bf(tt);
            }
        }
    }
    stage_tile(Wt2, Wlds, t);
    __syncthreads();

    #pragma unroll
    for (int i = 0; i < 2; ++i)
        #pragma unroll
        for (int ct = 0; ct < 8; ++ct) acc[i][ct] = (f32x4)0.f;

    #pragma unroll
    for (int kb = 0; kb < 4; ++kb) {
        int bo = kb * 64 + q * 16;
        bf16x8 af0 = frag8(Alds, (w * 2 + 0) * 16 + m, bo);
        bf16x8 af1 = frag8(Alds, (w * 2 + 1) * 16 + m, bo);
        #pragma unroll
        for (int ct = 0; ct < 8; ++ct) {
            bf16x8 bfv = frag8(Wlds, ct * 16 + m, bo);
            acc[0][ct] = __builtin_amdgcn_mfma_f32_16x16x32_bf16(af0, bfv, acc[0][ct], 0, 0, 0);
            acc[1][ct] = __builtin_amdgcn_mfma_f32_16x16x32_bf16(af1, bfv, acc[1][ct], 0, 0, 0);
        }
    }

    #pragma unroll
    for (int ct = 0; ct < 8; ++ct) {
        int col = ct * 16 + m;
        float bb = b2[col];
        #pragma unroll
        for (int i = 0; i < 2; ++i) {
            int rbase = row0 + (w * 2 + i) * 16 + q * 4;
            #pragma unroll
            for (int r = 0; r < 4; ++r) {
                int gr = rbase + r;
                if (gr < N_NODES) {
                    float v = acc[i][ct][r] + bb;
                    if (mode) xbout[gr * DIM + col] = f2bf(fmaxf(v, 0.f));
                    else      outf[gr * DIM + col] = v;
                }
            }
        }
    }
}

// ---------------------------------------------------------------------------
// Workspace (float units):
//   xb     @ 12,800,512 : 12.8M ushort  [x_bf16 / interlayer]
//   ab     @ 19,200,512 : 12.8M ushort  [agg output]
//   ints   @ 25,600,512 : bbuf[NBK*BCAP] | bcursor[782] | pad[2] |
//                         stats[512 floats: cs0 cq0 cs1 cq1] |
//                         nstart[100,000] | ndeg[100,000] | Wt x4 (bf16)
// One memset covers bcursor..stats (1296 ints).
// ---------------------------------------------------------------------------
extern "C" void kernel_launch(void* const* d_in, const int* in_sizes, int n_in,
                              void* d_out, int out_size, void* d_ws, size_t ws_size,
                              hipStream_t stream)
{
    const float* x    = (const float*)d_in[0];
    const int*   ei   = (const int*)d_in[1];
    const float* W1_0 = (const float*)d_in[2];
    const float* b1_0 = (const float*)d_in[3];
    const float* g_0  = (const float*)d_in[4];
    const float* be_0 = (const float*)d_in[5];
    const float* W2_0 = (const float*)d_in[6];
    const float* b2_0 = (const float*)d_in[7];
    const float* W1_1 = (const float*)d_in[8];
    const float* b1_1 = (const float*)d_in[9];
    const float* g_1  = (const float*)d_in[10];
    const float* be_1 = (const float*)d_in[11];
    const float* W2_1 = (const float*)d_in[12];
    const float* b2_1 = (const float*)d_in[13];
    float* out = (float*)d_out;
    float* ws  = (float*)d_ws;

    unsigned short* xb = (unsigned short*)(ws + 12800512);
    unsigned short* ab = (unsigned short*)(ws + 19200512);
    int* ibase    = (int*)(ws + 25600512);
    int* bbuf     = ibase;
    int* bcursor  = ibase + NBK * BCAP;
    float* stats  = (float*)(bcursor + NBK + 2);       // 512 floats
    float* cs0 = stats, *cq0 = stats + 128, *cs1 = stats + 256, *cq1 = stats + 384;
    int* nstart   = (int*)(stats + 512);
    int* ndeg     = nstart + N_NODES;
    unsigned short* wt10 = (unsigned short*)(ndeg + N_NODES);
    unsigned short* wt20 = wt10 + 16384;
    unsigned short* wt11 = wt10 + 32768;
    unsigned short* wt21 = wt10 + 49152;

    dim3 blk(256);
    int fill_blocks = (N_EDGES + 8191) / 8192;         // 196

    // ---- one-time converts + bucket build + one-time counting sort ----
    cvt_k<<<12756, blk, 0, stream>>>(x, xb, W1_0, W2_0, W1_1, W2_1, wt10);
    hipMemsetAsync(bcursor, 0, (NBK + 2 + 512) * sizeof(int), stream);
    bfill2_k<<<fill_blocks, 512, 0, stream>>>(ei, bcursor, bbuf);
    bsort_k<<<NBK, blk, 0, stream>>>(bcursor, bbuf, nstart, ndeg);

    // ---- layer 0 ----
    aggstats_k<<<MT_TILES, 512, 0, stream>>>(xb, bbuf, nstart, ndeg, ab,
                                             wt10, b1_0, cs0, cq0);
    fused_mlp_k<<<MT_TILES, blk, 0, stream>>>(ab, cs0, cq0, g_0, be_0,
                                              wt10, b1_0, wt20, b2_0,
                                              nullptr, xb, 1);

    // ---- layer 1 ----
    aggstats_k<<<MT_TILES, 512, 0, stream>>>(xb, bbuf, nstart, ndeg, ab,
                                             wt11, b1_1, cs1, cq1);
    fused_mlp_k<<<MT_TILES, blk, 0, stream>>>(ab, cs1, cq1, g_1, be_1,
                                              wt11, b1_1, wt21, b2_1,
                                              out, nullptr, 0);
}

// Round 10
// 414.183 us; speedup vs baseline: 1.0905x; 1.0865x over previous
//
#include <hip/hip_runtime.h>

#define N_NODES 100000
#define N_EDGES 1600000
#define DIM 128

#define BK_BITS 7
#define BK_NODES 128
#define NBK ((N_NODES + BK_NODES - 1) / BK_NODES)   // 782
#define BCAP 2688                 // mean 2046/bucket, sd ~45 -> 14 sigma
#define MT_TILES ((N_NODES + 127) / 128)            // 782

// pre_k block ranges: [0,196) bfill | [196, 6446) x-cvt | [6446, 6574) w-cvt
#define PRE_BFILL 196
#define PRE_X     6250
#define PRE_W     128
#define PRE_BLOCKS (PRE_BFILL + PRE_X + PRE_W)      // 6574

typedef __attribute__((ext_vector_type(8))) short bf16x8;
typedef __attribute__((ext_vector_type(4))) float f32x4;

__device__ inline unsigned short f2bf(float f) {
    unsigned u = __builtin_bit_cast(unsigned, f);
    return (unsigned short)((u + 0x7FFFu + ((u >> 16) & 1u)) >> 16);   // RNE
}
__device__ inline float bf2f(unsigned short u) {
    unsigned v = ((unsigned)u) << 16;
    return __builtin_bit_cast(float, v);
}

// Direct global->LDS 16B DMA. LDS dest = wave-uniform base + lane*16.
__device__ __forceinline__ void gl16(const void* g, void* l) {
    __builtin_amdgcn_global_load_lds(
        (const __attribute__((address_space(1))) void*)g,
        (__attribute__((address_space(3))) void*)l, 16, 0, 0);
}

// 256-thread stage of a 128-row x 256B tile: linear LDS dest, inverse-
// swizzled global src. Swizzle: byte-in-row ^= (row&7)<<4.
__device__ __forceinline__ void stage_tile(const void* gbase, void* lds, int t) {
    const int wvS = t >> 6, lnS = t & 63;
    #pragma unroll
    for (int k = 0; k < 8; ++k) {
        int chunk = wvS * 8 + k;                 // 0..31 (1KB each)
        int r = chunk * 4 + (lnS >> 4);          // row 0..127
        int gb = ((lnS & 15) * 16) ^ ((r & 7) << 4);
        gl16((const char*)gbase + (size_t)r * 256 + gb,
             (char*)lds + chunk * 1024);
    }
}

// Swizzled bf16x8 fragment read (matching the staging swizzle).
__device__ __forceinline__ bf16x8 frag8(const unsigned short* lds, int row, int bo) {
    return *(const bf16x8*)((const char*)lds + row * 256 + (bo ^ ((row & 7) << 4)));
}

// ===========================================================================
// Merged preprocessing: bucket fill (blocks 0..195, starts first to overlap
// its atomic/latency-bound work with the BW-bound converts) + x->bf16
// convert + all 4 weight transposes. All three are independent.
// ===========================================================================
__global__ __launch_bounds__(512) void pre_k(const int* __restrict__ ei,
                                             int* __restrict__ bcursor,
                                             int* __restrict__ bbuf,
                                             const float* __restrict__ x,
                                             unsigned short* __restrict__ xb,
                                             const float* __restrict__ Wa,
                                             const float* __restrict__ Wb,
                                             const float* __restrict__ Wc,
                                             const float* __restrict__ Wd,
                                             unsigned short* __restrict__ wt)
{
    __shared__ int hist[NBK];
    __shared__ int cur[NBK];
    const int t = threadIdx.x;
    const int b = blockIdx.x;

    if (b < PRE_BFILL) {
        // ---- bucket fill (round-6 bfill2_k body) ----
        const int e0 = b * 8192;
        for (int i = t; i < NBK; i += 512) hist[i] = 0;
        __syncthreads();
        #pragma unroll
        for (int i = 0; i < 16; ++i) {
            int e = e0 + i * 512 + t;
            if (e < N_EDGES) atomicAdd(&hist[ei[N_EDGES + e] >> BK_BITS], 1);
        }
        __syncthreads();
        for (int i = t; i < NBK; i += 512) {
            int h = hist[i];
            cur[i] = h ? atomicAdd(bcursor + i, h) : 0;
        }
        __syncthreads();
        #pragma unroll
        for (int i = 0; i < 16; ++i) {
            int e = e0 + i * 512 + t;
            if (e < N_EDGES) {
                int src = ei[e];
                int dst = ei[N_EDGES + e];
                int bk = dst >> BK_BITS;
                int pos = atomicAdd(&cur[bk], 1);
                if (pos < BCAP) bbuf[bk * BCAP + pos] = ((dst & (BK_NODES - 1)) << 17) | src;
            }
        }
    } else if (b < PRE_BFILL + PRE_X) {
        // ---- x -> bf16 (vectorized) ----
        int i = ((b - PRE_BFILL) * 512 + t) * 4;
        float4 v = *(const float4*)(x + i);
        unsigned short o[4] = {f2bf(v.x), f2bf(v.y), f2bf(v.z), f2bf(v.w)};
        xb[i] = o[0]; xb[i+1] = o[1]; xb[i+2] = o[2]; xb[i+3] = o[3];
    } else {
        // ---- weight transpose+convert: Wt[n*128+k] = bf16(W[k*128+n]) ----
        int id = (b - PRE_BFILL - PRE_X) * 512 + t;    // 0..65535
        int which = id >> 14, rem = id & 16383;
        const float* W = (which == 0) ? Wa : (which == 1) ? Wb : (which == 2) ? Wc : Wd;
        int n = rem >> 7, k = rem & 127;
        wt[which * 16384 + n * DIM + k] = f2bf(W[k * DIM + n]);
    }
}

// ===========================================================================
// ONE-TIME counting sort per bucket -> CSR (nstart/ndeg), bbuf in place.
// ===========================================================================
__global__ __launch_bounds__(256) void bsort_k(const int* __restrict__ bcursor,
                                               int* __restrict__ bbuf,
                                               int* __restrict__ nstart,
                                               int* __restrict__ ndeg)
{
    __shared__ int elist[BCAP];
    __shared__ int bins[BK_NODES];
    __shared__ int cur[BK_NODES];
    __shared__ int scanb[BK_NODES];

    const int t = threadIdx.x;
    const int b = blockIdx.x;

    if (t < BK_NODES) bins[t] = 0;
    __syncthreads();

    int n = bcursor[b];
    if (n > BCAP) n = BCAP;
    int* bp = bbuf + b * BCAP;

    int wreg[(BCAP + 255) / 256];                 // 11
    const int nIter = (n + 255) >> 8;
    #pragma unroll
    for (int i = 0; i < (BCAP + 255) / 256; ++i) wreg[i] = -1;
    for (int i = 0; i < nIter; ++i) {
        int idx = t + (i << 8);
        if (idx < n) {
            int word = bp[idx];
            wreg[i] = word;
            atomicAdd(&bins[word >> 17], 1);
        }
    }
    __syncthreads();

    if (t < BK_NODES) scanb[t] = bins[t];
    __syncthreads();
    #pragma unroll
    for (int off = 1; off < BK_NODES; off <<= 1) {
        int add = (t >= off && t < BK_NODES) ? scanb[t - off] : 0;
        __syncthreads();
        if (t < BK_NODES) scanb[t] += add;
        __syncthreads();
    }
    if (t < BK_NODES) {
        cur[t] = scanb[t] - bins[t];
        int node = b * BK_NODES + t;
        if (node < N_NODES) {
            nstart[node] = b * BCAP + (scanb[t] - bins[t]);
            ndeg[node] = bins[t];
        }
    }
    __syncthreads();

    for (int i = 0; i < nIter; ++i) {
        int word = wreg[i];
        if (word >= 0) {
            int dl = word >> 17;
            int pos = atomicAdd(&cur[dl], 1);
            elist[pos] = word & 0x1FFFF;
        }
    }
    __syncthreads();

    for (int i = t; i < n; i += 256) bp[i] = elist[i];      // coalesced writeback
}

// ===========================================================================
// CSR mean-aggregation gather (bf16): grid-strided, 2 nodes/wave-iter,
// node split across two 16-lane groups, unroll-4 (proven round-4/6 version).
// ===========================================================================
__global__ __launch_bounds__(512) void agg_csr_k(const unsigned short* __restrict__ xb,
                                                 const int* __restrict__ elist,
                                                 const int* __restrict__ nstart,
                                                 const int* __restrict__ ndeg,
                                                 unsigned short* __restrict__ ab)
{
    const int t = threadIdx.x;
    const int wv = t >> 6;              // wave in block: 0..7
    const int lane = t & 63;
    const int qw = lane >> 4;           // 0..3
    const int c  = lane & 15;           // col chunk: cols c*8 .. c*8+7
    const int sub = qw & 1;             // which half of the edge list
    const int nn  = qw >> 1;            // node within the pair

    const int g  = blockIdx.x * 8 + wv; // global wave id
    const int NW = gridDim.x * 8;       // total waves

    for (int n0 = g * 2; n0 < N_NODES; n0 += NW * 2) {
        int node = n0 + nn;
        bool valid = node < N_NODES;
        int beg = 0, deg = 0;
        if (valid) { beg = nstart[node]; deg = ndeg[node]; }
        int mid = beg + ((deg + 1) >> 1);
        int end = beg + deg;
        int lo = sub ? mid : beg;
        int hi = sub ? end : mid;

        float a[8];
        #pragma unroll
        for (int u = 0; u < 8; ++u) a[u] = 0.f;

        int e = lo;
        for (; e + 4 <= hi; e += 4) {
            int s0 = elist[e], s1 = elist[e + 1], s2 = elist[e + 2], s3 = elist[e + 3];
            bf16x8 v0 = *(const bf16x8*)(xb + s0 * DIM + c * 8);
            bf16x8 v1 = *(const bf16x8*)(xb + s1 * DIM + c * 8);
            bf16x8 v2 = *(const bf16x8*)(xb + s2 * DIM + c * 8);
            bf16x8 v3 = *(const bf16x8*)(xb + s3 * DIM + c * 8);
            #pragma unroll
            for (int u = 0; u < 8; ++u)
                a[u] += (bf2f((unsigned short)v0[u]) + bf2f((unsigned short)v1[u]))
                      + (bf2f((unsigned short)v2[u]) + bf2f((unsigned short)v3[u]));
        }
        for (; e < hi; ++e) {
            int s0 = elist[e];
            bf16x8 v0 = *(const bf16x8*)(xb + s0 * DIM + c * 8);
            #pragma unroll
            for (int u = 0; u < 8; ++u) a[u] += bf2f((unsigned short)v0[u]);
        }

        // combine the two half-sums for this node (lanes qw0<->qw1, qw2<->qw3)
        #pragma unroll
        for (int u = 0; u < 8; ++u) a[u] += __shfl_xor(a[u], 16, 64);

        if (valid && sub == 0) {
            float inv = 1.0f / fmaxf((float)deg, 1.0f);
            bf16x8 xv = *(const bf16x8*)(xb + node * DIM + c * 8);
            bf16x8 o;
            #pragma unroll
            for (int u = 0; u < 8; ++u)
                o[u] = (short)f2bf(bf2f((unsigned short)xv[u]) + a[u] * inv);
            *(bf16x8*)(ab + node * DIM + c * 8) = o;
        }
    }
}

// ===========================================================================
// Stats-only GEMM1: MFMA A(bf16)@W1 + b1, accumulate BN colsum/colsq ONLY.
// Staging via global_load_lds width=16 (round-6 proven 256-thr version).
// ===========================================================================
__global__ __launch_bounds__(256) void gemm1_stats_k(
    const unsigned short* __restrict__ ab,
    const unsigned short* __restrict__ Wt, const float* __restrict__ bias,
    float* __restrict__ colsum, float* __restrict__ colsq)
{
    __shared__ unsigned short Alds[128 * 128];
    __shared__ unsigned short Wlds[128 * 128];
    __shared__ float cstat[256];

    const int t = threadIdx.x;
    const int row0 = blockIdx.x * 128;
    if (t < 256) cstat[t] = 0.f;

    stage_tile((const char*)ab + (size_t)row0 * 256, Alds, t);
    stage_tile(Wt, Wlds, t);
    __syncthreads();                 // compiler drains vmcnt before barrier

    const int w = t >> 6, lane = t & 63;
    const int m = lane & 15, q = lane >> 4;

    f32x4 acc[2][8];
    #pragma unroll
    for (int i = 0; i < 2; ++i)
        #pragma unroll
        for (int ct = 0; ct < 8; ++ct) acc[i][ct] = (f32x4)0.f;

    #pragma unroll
    for (int kb = 0; kb < 4; ++kb) {
        int bo = kb * 64 + q * 16;
        bf16x8 af0 = frag8(Alds, (w * 2 + 0) * 16 + m, bo);
        bf16x8 af1 = frag8(Alds, (w * 2 + 1) * 16 + m, bo);
        #pragma unroll
        for (int ct = 0; ct < 8; ++ct) {
            bf16x8 bfv = frag8(Wlds, ct * 16 + m, bo);
            acc[0][ct] = __builtin_amdgcn_mfma_f32_16x16x32_bf16(af0, bfv, acc[0][ct], 0, 0, 0);
            acc[1][ct] = __builtin_amdgcn_mfma_f32_16x16x32_bf16(af1, bfv, acc[1][ct], 0, 0, 0);
        }
    }

    #pragma unroll
    for (int ct = 0; ct < 8; ++ct) {
        int col = ct * 16 + m;
        float bb = bias[col];
        float ps = 0.f, pq = 0.f;
        #pragma unroll
        for (int i = 0; i < 2; ++i) {
            int rbase = row0 + (w * 2 + i) * 16 + q * 4;
            #pragma unroll
            for (int r = 0; r < 4; ++r) {
                if (rbase + r < N_NODES) {
                    float v = acc[i][ct][r] + bb;
                    ps += v; pq += v * v;
                }
            }
        }
        atomicAdd(&cstat[col], ps);
        atomicAdd(&cstat[128 + col], pq);
    }
    __syncthreads();
    if (t < 128) {
        atomicAdd(colsum + t, cstat[t]);
        atomicAdd(colsq + t, cstat[128 + t]);
    }
}

// ===========================================================================
// Fused MLP (round-6 proven 256-thr version): bnstats folded -> GEMM1 ->
// BN+ReLU t into LDS -> W2 restage -> GEMM2 -> out.
// mode 1: bf16 relu -> xbout ; mode 0: fp32 -> outf
// ===========================================================================
__global__ __launch_bounds__(256) void fused_mlp_k(
    const unsigned short* __restrict__ ab,
    const float* __restrict__ colsum, const float* __restrict__ colsq,
    const float* __restrict__ gamma, const float* __restrict__ beta,
    const unsigned short* __restrict__ Wt1, const float* __restrict__ b1,
    const unsigned short* __restrict__ Wt2, const float* __restrict__ b2,
    float* __restrict__ outf, unsigned short* __restrict__ xbout, int mode)
{
    __shared__ unsigned short Alds[128 * 128];
    __shared__ unsigned short Wlds[128 * 128];
    __shared__ float ssc[384];    // scale | shift | b1

    const int t = threadIdx.x;
    const int row0 = blockIdx.x * 128;

    if (t < 128) {
        const float inv_n = 1.0f / (float)N_NODES;
        float mu = colsum[t] * inv_n;
        float var = colsq[t] * inv_n - mu * mu;   // biased variance (torch BN)
        float sc = gamma[t] * rsqrtf(var + 1e-5f);
        ssc[t] = sc;
        ssc[128 + t] = beta[t] - mu * sc;
        ssc[256 + t] = b1[t];
    }

    stage_tile((const char*)ab + (size_t)row0 * 256, Alds, t);
    stage_tile(Wt1, Wlds, t);
    __syncthreads();

    const int w = t >> 6, lane = t & 63;
    const int m = lane & 15, q = lane >> 4;

    f32x4 acc[2][8];
    #pragma unroll
    for (int i = 0; i < 2; ++i)
        #pragma unroll
        for (int ct = 0; ct < 8; ++ct) acc[i][ct] = (f32x4)0.f;

    #pragma unroll
    for (int kb = 0; kb < 4; ++kb) {
        int bo = kb * 64 + q * 16;
        bf16x8 af0 = frag8(Alds, (w * 2 + 0) * 16 + m, bo);
        bf16x8 af1 = frag8(Alds, (w * 2 + 1) * 16 + m, bo);
        #pragma unroll
        for (int ct = 0; ct < 8; ++ct) {
            bf16x8 bfv = frag8(Wlds, ct * 16 + m, bo);
            acc[0][ct] = __builtin_amdgcn_mfma_f32_16x16x32_bf16(af0, bfv, acc[0][ct], 0, 0, 0);
            acc[1][ct] = __builtin_amdgcn_mfma_f32_16x16x32_bf16(af1, bfv, acc[1][ct], 0, 0, 0);
        }
    }

    __syncthreads();   // all waves done reading Alds (A) and Wlds (W1)

    // BN + ReLU epilogue: scatter t into Alds (swizzled bf16), restage W2.
    #pragma unroll
    for (int ct = 0; ct < 8; ++ct) {
        int col = ct * 16 + m;
        float sc = ssc[col], sh = ssc[128 + col], bb = ssc[256 + col];
        #pragma unroll
        for (int i = 0; i < 2; ++i) {
            int rr0 = (w * 2 + i) * 16 + q * 4;
            #pragma unroll
            for (int r = 0; r < 4; ++r) {
                int row = rr0 + r;
                float v = acc[i][ct][r] + bb;
                float tt = fmaxf(v * sc + sh, 0.f);
                *(unsigned short*)((char*)Alds + row * 256 +
                                   ((col * 2) ^ ((row & 7) << 4))) = f2bf(tt);
            }
        }
    }
    stage_tile(Wt2, Wlds, t);
    __syncthreads();

    #pragma unroll
    for (int i = 0; i < 2; ++i)
        #pragma unroll
        for (int ct = 0; ct < 8; ++ct) acc[i][ct] = (f32x4)0.f;

    #pragma unroll
    for (int kb = 0; kb < 4; ++kb) {
        int bo = kb * 64 + q * 16;
        bf16x8 af0 = frag8(Alds, (w * 2 + 0) * 16 + m, bo);
        bf16x8 af1 = frag8(Alds, (w * 2 + 1) * 16 + m, bo);
        #pragma unroll
        for (int ct = 0; ct < 8; ++ct) {
            bf16x8 bfv = frag8(Wlds, ct * 16 + m, bo);
            acc[0][ct] = __builtin_amdgcn_mfma_f32_16x16x32_bf16(af0, bfv, acc[0][ct], 0, 0, 0);
            acc[1][ct] = __builtin_amdgcn_mfma_f32_16x16x32_bf16(af1, bfv, acc[1][ct], 0, 0, 0);
        }
    }

    #pragma unroll
    for (int ct = 0; ct < 8; ++ct) {
        int col = ct * 16 + m;
        float bb = b2[col];
        #pragma unroll
        for (int i = 0; i < 2; ++i) {
            int rbase = row0 + (w * 2 + i) * 16 + q * 4;
            #pragma unroll
            for (int r = 0; r < 4; ++r) {
                int gr = rbase + r;
                if (gr < N_NODES) {
                    float v = acc[i][ct][r] + bb;
                    if (mode) xbout[gr * DIM + col] = f2bf(fmaxf(v, 0.f));
                    else      outf[gr * DIM + col] = v;
                }
            }
        }
    }
}

// ---------------------------------------------------------------------------
// Workspace (float units):
//   xb     @ 12,800,512 : 12.8M ushort  [x_bf16 / interlayer]
//   ab     @ 19,200,512 : 12.8M ushort  [agg output]
//   ints   @ 25,600,512 : bbuf[NBK*BCAP] | bcursor[782] | pad[2] |
//                         stats[512 floats: cs0 cq0 cs1 cq1] |
//                         nstart[100,000] | ndeg[100,000] | Wt x4 (bf16)
// One memset covers bcursor..stats (1296 ints).
// ---------------------------------------------------------------------------
extern "C" void kernel_launch(void* const* d_in, const int* in_sizes, int n_in,
                              void* d_out, int out_size, void* d_ws, size_t ws_size,
                              hipStream_t stream)
{
    const float* x    = (const float*)d_in[0];
    const int*   ei   = (const int*)d_in[1];
    const float* W1_0 = (const float*)d_in[2];
    const float* b1_0 = (const float*)d_in[3];
    const float* g_0  = (const float*)d_in[4];
    const float* be_0 = (const float*)d_in[5];
    const float* W2_0 = (const float*)d_in[6];
    const float* b2_0 = (const float*)d_in[7];
    const float* W1_1 = (const float*)d_in[8];
    const float* b1_1 = (const float*)d_in[9];
    const float* g_1  = (const float*)d_in[10];
    const float* be_1 = (const float*)d_in[11];
    const float* W2_1 = (const float*)d_in[12];
    const float* b2_1 = (const float*)d_in[13];
    float* out = (float*)d_out;
    float* ws  = (float*)d_ws;

    unsigned short* xb = (unsigned short*)(ws + 12800512);
    unsigned short* ab = (unsigned short*)(ws + 19200512);
    int* ibase    = (int*)(ws + 25600512);
    int* bbuf     = ibase;
    int* bcursor  = ibase + NBK * BCAP;
    float* stats  = (float*)(bcursor + NBK + 2);       // 512 floats
    float* cs0 = stats, *cq0 = stats + 128, *cs1 = stats + 256, *cq1 = stats + 384;
    int* nstart   = (int*)(stats + 512);
    int* ndeg     = nstart + N_NODES;
    unsigned short* wt10 = (unsigned short*)(ndeg + N_NODES);
    unsigned short* wt20 = wt10 + 16384;
    unsigned short* wt11 = wt10 + 32768;
    unsigned short* wt21 = wt10 + 49152;

    dim3 blk(256);

    // ---- one-time: memset -> merged (bfill | x-cvt | w-cvt) -> sort ----
    hipMemsetAsync(bcursor, 0, (NBK + 2 + 512) * sizeof(int), stream);
    pre_k<<<PRE_BLOCKS, 512, 0, stream>>>(ei, bcursor, bbuf,
                                          x, xb, W1_0, W2_0, W1_1, W2_1, wt10);
    bsort_k<<<NBK, blk, 0, stream>>>(bcursor, bbuf, nstart, ndeg);

    // ---- layer 0 ----
    agg_csr_k<<<1024, 512, 0, stream>>>(xb, bbuf, nstart, ndeg, ab);
    gemm1_stats_k<<<MT_TILES, blk, 0, stream>>>(ab, wt10, b1_0, cs0, cq0);
    fused_mlp_k<<<MT_TILES, blk, 0, stream>>>(ab, cs0, cq0, g_0, be_0,
                                              wt10, b1_0, wt20, b2_0,
                                              nullptr, xb, 1);

    // ---- layer 1 ----
    agg_csr_k<<<1024, 512, 0, stream>>>(xb, bbuf, nstart, ndeg, ab);
    gemm1_stats_k<<<MT_TILES, blk, 0, stream>>>(ab, wt11, b1_1, cs1, cq1);
    fused_mlp_k<<<MT_TILES, blk, 0, stream>>>(ab, cs1, cq1, g_1, be_1,
                                              wt11, b1_1, wt21, b2_1,
                                              out, nullptr, 0);
}